// Round 17
// baseline (44.137 us; speedup 1.0000x reference)
//
#include <hip/hip_runtime.h>
#include <math.h>

#define CCH     128
#define HWTOK   4096
#define MROWS   512
#define THREADS 512    // main kernel: 8 waves/block, 512 blocks

using float16 = __attribute__((ext_vector_type(16))) float;
using f4      = __attribute__((ext_vector_type(4))) float;
using i4      = __attribute__((ext_vector_type(4))) int;

__device__ __forceinline__ float fmax3(float a, float b, float c) {
    return fmaxf(fmaxf(a, b), c);   // clang fuses to v_max3_f32
}

// pack 8 f32 -> 8 fp8 e4m3 (OCP) bytes via HW cvt, as two dwords
__device__ __forceinline__ void pack_fp8x8_w(const float* v, int& w0, int& w1) {
    w0 = 0; w1 = 0;
    w0 = __builtin_amdgcn_cvt_pk_fp8_f32(v[0], v[1], w0, false);
    w0 = __builtin_amdgcn_cvt_pk_fp8_f32(v[2], v[3], w0, true);
    w1 = __builtin_amdgcn_cvt_pk_fp8_f32(v[4], v[5], w1, false);
    w1 = __builtin_amdgcn_cvt_pk_fp8_f32(v[6], v[7], w1, true);
}
__device__ __forceinline__ long pack_fp8x8(const float* v) {
    int w0, w1; pack_fp8x8_w(v, w0, w1);
    return (long)(unsigned)w0 | ((long)w1 << 32);
}

// ws layout: [0,64K) fp8 row-frag table | [512K,1M) token norms f32 | [1M,17M) x fp8 frags
#define WS_NORM_OFF  (512u * 1024u)
#define WS_XF_OFF    (1024u * 1024u)
#define WS_NEEDED    (WS_XF_OFF + (size_t)131072 * 128)

// ---------------------------------------------------------------------------
// Prep A: pre-normalized memory rows as fp8 e4m3 MFMA A-fragments (64 KB).
// fid = (mt*8 + kstep)*64 + lane, lane = hi*32 + r5 holds
//   fp8(memory[mt*32 + r5][kstep*16 + hi*8 + j] * rinv(row)), j = 0..7.
// ---------------------------------------------------------------------------
__global__ __launch_bounds__(256) void frag_kernel(const float* __restrict__ mem,
                                                   long* __restrict__ wsfrag) {
    int fid   = blockIdx.x * 256 + threadIdx.x;   // 0..8191
    int mt    = fid >> 9;
    int rem   = fid & 511;
    int kstep = rem >> 6;
    int l     = rem & 63;
    int hi    = l >> 5, r5 = l & 31;
    int row   = mt * 32 + r5;
    int k0    = kstep * 16 + hi * 8;

    const float* mr = mem + (size_t)row * CCH;
    float s = 0.f;
    #pragma unroll
    for (int c = 0; c < CCH; c += 4) {
        f4 v = *reinterpret_cast<const f4*>(mr + c);
        s += v.x * v.x + v.y * v.y + v.z * v.z + v.w * v.w;
    }
    float sc = 1.0f / fmaxf(sqrtf(s), 1e-12f);

    float v[8];
    #pragma unroll
    for (int j = 0; j < 8; ++j) v[j] = mr[k0 + j] * sc;
    wsfrag[fid] = pack_fp8x8(v);
}

// ---------------------------------------------------------------------------
// Prep B: x -> fp8 B-fragments + per-token norm^2. Reads x in STORAGE-LINEAR
// order (f4, 256B segments/instr — the proven-clean pattern), transposes via
// LDS, writes fragments token-major: long index gt*16 + kstep*2 + hi holds
// fp8(x[token gt][kstep*16 + hi*8 + j]), j = 0..7. Writes are 32B contiguous
// per thread, 2KB contiguous per wave pair — fully linear. Norms in fp32.
// 2048 blocks x 256 thr; block = 64 tokens.
// ---------------------------------------------------------------------------
__global__ __launch_bounds__(256) void xprep_kernel(const float* __restrict__ x,
                                                    long* __restrict__ xf,
                                                    float* __restrict__ xnorm) {
    __shared__ float xs[CCH * 68];   // [c][t] padded (68 dwords: f4-aligned)

    const int tid = threadIdx.x;
    const int b   = blockIdx.x >> 6;             // 64 blocks/batch
    const int t0  = (blockIdx.x & 63) * 64;      // token base within batch
    const float* xb = x + (size_t)b * CCH * HWTOK + t0;

    // load 128 ch x 64 tok = 2048 f4, storage-linear
    #pragma unroll
    for (int j = 0; j < 8; ++j) {
        int idx = tid + j * 256;                 // 0..2047
        int c = idx >> 4, t4 = idx & 15;
        f4 v = *reinterpret_cast<const f4*>(xb + (size_t)c * HWTOK + t4 * 4);
        *reinterpret_cast<f4*>(&xs[c * 68 + t4 * 4]) = v;
    }
    __syncthreads();

    // convert: thread = (t, k2); handles ksteps {2k2, 2k2+1} x hi {0,1}
    const int t  = tid >> 2;
    const int k2 = tid & 3;
    float s = 0.f;
    int w[8];   // 4 longs as dword pairs, in long-index order k2*4 + kk*2 + hi
    #pragma unroll
    for (int kk = 0; kk < 2; ++kk) {
        #pragma unroll
        for (int hi = 0; hi < 2; ++hi) {
            float v[8];
            #pragma unroll
            for (int j = 0; j < 8; ++j) {
                int c = (2 * k2 + kk) * 16 + hi * 8 + j;
                v[j] = xs[c * 68 + t];
                s = fmaf(v[j], v[j], s);
            }
            pack_fp8x8_w(v, w[(kk * 2 + hi) * 2], w[(kk * 2 + hi) * 2 + 1]);
        }
    }
    // full norm^2: quad lanes (t fixed, k2 = 0..3) each summed 32 channels
    s += __shfl_xor(s, 1);
    s += __shfl_xor(s, 2);

    const long gt = (long)b * HWTOK + t0 + t;
    long* dst = xf + gt * 16 + k2 * 4;
    i4 a; a.x = w[0]; a.y = w[1]; a.z = w[2]; a.w = w[3];
    i4 c2; c2.x = w[4]; c2.y = w[5]; c2.z = w[6]; c2.w = w[7];
    *reinterpret_cast<i4*>(dst)     = a;
    *reinterpret_cast<i4*>(dst + 2) = c2;
    if (k2 == 0) xnorm[gt] = s;
}

// ---------------------------------------------------------------------------
// Main: r16 structure (fused clean fill + 64 KB fp8 table in LDS + max-only
// hot loop + rare exact-argmax path). x-read: 8 x dwordx2 pre-packed fragments
// + 1 norm (usefp8=1) — few enough loads to stay fully in flight — or the
// r16 inline f32 build (usefp8=0 fallback when ws is too small).
// ---------------------------------------------------------------------------
__global__ __launch_bounds__(THREADS, 2) void hardmem_mfma(
    const float* __restrict__ x, const float* __restrict__ mem,
    const long* __restrict__ wsfrag, const long* __restrict__ xf,
    const float* __restrict__ xnorm, const int usefp8,
    float* __restrict__ out)
{
    __shared__ long sfrag[8192];   // 64 KB — whole fp8 fragment table

    const int tid  = threadIdx.x;
    const int wid  = tid >> 6;                 // 0..7
    const int lane = tid & 63;
    const int l5   = lane & 31, hi = lane >> 5;

    const int b    = blockIdx.x >> 4;                    // 16 blocks/batch
    const int treg = (blockIdx.x & 15) * 256;            // block token region
    const int tb0  = treg + wid * 32;                    // wave token base
    float* obase   = out + (size_t)b * CCH * HWTOK;

    // ---- 1. zero-fill own region (r14-r16 proven-clean shape: 1 KB
    // contiguous per wave instruction; WRITE_SIZE byte-exact 65536 KB)
    {
        float* oreg = obase + treg;
        f4 z = {0.f, 0.f, 0.f, 0.f};
        #pragma unroll
        for (int i = 0; i < 16; ++i) {
            int idx = tid + i * THREADS;       // 0..8191
            int c = idx >> 6, o4 = idx & 63;
            *reinterpret_cast<f4*>(oreg + (size_t)c * HWTOK + o4 * 4) = z;
        }
    }

    // ---- 2. stage fp8 table -> LDS (64 KB, L2-hot)
    {
        const i4* wsv = reinterpret_cast<const i4*>(wsfrag);
        i4* sfv = reinterpret_cast<i4*>(sfrag);
        #pragma unroll
        for (int i = 0; i < 8; ++i) {
            int idx = tid + i * THREADS;       // 0..4095 i4s
            sfv[idx] = wsv[idx];
        }
    }

    // ---- 3. x B-fragment
    long bf[8];
    float n2;
    if (usefp8) {
        const long gt = (long)b * HWTOK + tb0 + l5;
        const long* xfp = xf + gt * 16 + hi;   // long index k*2 + hi
        #pragma unroll
        for (int k = 0; k < 8; ++k) bf[k] = xfp[k * 2];
        n2 = xnorm[gt];                         // full norm^2 (both halves)
    } else {
        const float* xt = x + (size_t)b * CCH * HWTOK + tb0 + l5;
        float v[64];
        #pragma unroll
        for (int j = 0; j < 64; ++j) {
            const int c = (j >> 3) * 16 + hi * 8 + (j & 7);
            v[j] = xt[(size_t)c * HWTOK];
        }
        float s = 0.f;
        #pragma unroll
        for (int k = 0; k < 8; ++k) {
            #pragma unroll
            for (int j = 0; j < 8; ++j) s = fmaf(v[k * 8 + j], v[k * 8 + j], s);
            bf[k] = pack_fp8x8(&v[k * 8]);
        }
        n2 = s + __shfl_xor(s, 32);             // halves hold half the channels
    }

    __syncthreads();   // sfrag visible + fill stores drained

    // ---- 4. hot loop: max-only over 512 rows, fp8 MFMA, A-frags from LDS
    float bmax = -1e30f;
    for (int mt = 0; mt < 16; ++mt) {
        long af[8];
        #pragma unroll
        for (int k = 0; k < 8; ++k)
            af[k] = sfrag[(mt * 8 + k) * 64 + lane];

        float16 acc;
        #pragma unroll
        for (int r = 0; r < 16; ++r) acc[r] = 0.f;
        #pragma unroll
        for (int k = 0; k < 8; ++k)
            acc = __builtin_amdgcn_mfma_f32_32x32x16_fp8_fp8(af[k], bf[k], acc, 0, 0, 0);

        float m0 = fmax3(acc[0], acc[1], acc[2]);
        float m1 = fmax3(acc[3], acc[4], acc[5]);
        float m2 = fmax3(acc[6], acc[7], acc[8]);
        float m3 = fmax3(acc[9], acc[10], acc[11]);
        float m4 = fmax3(acc[12], acc[13], acc[14]);
        bmax = fmaxf(bmax, fmax3(fmax3(m0, m1, m2), fmax3(m3, m4, acc[15]), bmax));
    }

    // ---- threshold: bv/||x|| > 0.8  <=>  bv > 0.8*||x|| (norm > 0)
    bmax = fmaxf(bmax, __shfl_xor(bmax, 32));   // merge hi-half rows
    const bool msk = bmax > 0.8f * fmaxf(sqrtf(n2), 1e-12f);

    const unsigned long long wb = __ballot(msk);
    if (wb == 0ULL) return;   // common case: zeros already in place

    // ---- rare path: exact argmax recompute (identical MFMAs), overwrite hits
    float bestv = -1e30f; int besti = 0;
    for (int mt = 0; mt < 16; ++mt) {
        long af[8];
        #pragma unroll
        for (int k = 0; k < 8; ++k)
            af[k] = sfrag[(mt * 8 + k) * 64 + lane];
        float16 acc;
        #pragma unroll
        for (int r = 0; r < 16; ++r) acc[r] = 0.f;
        #pragma unroll
        for (int k = 0; k < 8; ++k)
            acc = __builtin_amdgcn_mfma_f32_32x32x16_fp8_fp8(af[k], bf[k], acc, 0, 0, 0);
        const int rbase = mt * 32 + 4 * hi;
        #pragma unroll
        for (int r = 0; r < 16; ++r) {
            // C/D map (shape-determined): row=(reg&3)+8*(reg>>2)+4*(lane>>5)
            const int row = rbase + (r & 3) + 8 * (r >> 2);
            if (acc[r] > bestv) { bestv = acc[r]; besti = row; }
        }
    }
    float ov = __shfl_xor(bestv, 32);
    int   oi = __shfl_xor(besti, 32);
    if (ov > bestv || (ov == bestv && oi < besti)) { bestv = ov; besti = oi; }

    if (msk) {   // overwrite ONLY hit tokens
        const int t = tb0 + l5;
        const float* mrow = mem + (size_t)besti * CCH;
        #pragma unroll 8
        for (int k = 0; k < 64; ++k) {
            int c = hi + 2 * k;
            obase[(size_t)c * HWTOK + t] = mrow[c];
        }
    }
}

// ---------------------------------------------------------------------------
extern "C" void kernel_launch(void* const* d_in, const int* in_sizes, int n_in,
                              void* d_out, int out_size, void* d_ws, size_t ws_size,
                              hipStream_t stream) {
    const float* x   = (const float*)d_in[0];   // [32,128,64,64]
    const float* mem = (const float*)d_in[1];   // [512,128]
    float* out       = (float*)d_out;

    char* ws      = (char*)d_ws;
    long* wsfrag  = (long*)ws;                          // 64 KB table
    float* xnorm  = (float*)(ws + WS_NORM_OFF);         // 512 KB norms
    long* xf      = (long*)(ws + WS_XF_OFF);            // 16 MB x fp8 frags

    frag_kernel<<<32, 256, 0, stream>>>(mem, wsfrag);
    if (ws_size >= WS_NEEDED) {
        xprep_kernel<<<2048, 256, 0, stream>>>(x, xf, xnorm);
        hardmem_mfma<<<512, THREADS, 0, stream>>>(x, mem, wsfrag, xf, xnorm, 1, out);
    } else {
        hardmem_mfma<<<512, THREADS, 0, stream>>>(x, mem, wsfrag, nullptr, nullptr, 0, out);
    }
}

// Round 18
// 39.060 us; speedup vs baseline: 1.1300x; 1.1300x over previous
//
#include <hip/hip_runtime.h>
#include <math.h>

#define CCH     128
#define HWTOK   4096
#define MROWS   512
#define THREADS 1024   // 16 waves; 256 blocks = 1 block/CU

using float16 = __attribute__((ext_vector_type(16))) float;
using f4      = __attribute__((ext_vector_type(4))) float;
using f2      = __attribute__((ext_vector_type(2))) float;
using i4      = __attribute__((ext_vector_type(4))) int;

__device__ __forceinline__ float fmax3(float a, float b, float c) {
    return fmaxf(fmaxf(a, b), c);   // clang fuses to v_max3_f32
}

// pack 8 f32 -> 8 fp8 e4m3 (OCP) bytes in ascending order, via HW cvt
__device__ __forceinline__ long pack_fp8x8(const float* v) {
    int w0 = 0, w1 = 0;
    w0 = __builtin_amdgcn_cvt_pk_fp8_f32(v[0], v[1], w0, false);
    w0 = __builtin_amdgcn_cvt_pk_fp8_f32(v[2], v[3], w0, true);
    w1 = __builtin_amdgcn_cvt_pk_fp8_f32(v[4], v[5], w1, false);
    w1 = __builtin_amdgcn_cvt_pk_fp8_f32(v[6], v[7], w1, true);
    return (long)(unsigned)w0 | ((long)w1 << 32);
}

// ---------------------------------------------------------------------------
// Prep: pre-normalized memory rows as fp8 e4m3 MFMA A-fragments (64 KB table).
// fid = (mt*8 + kstep)*64 + lane, lane = hi*32 + r5 holds
//   fp8(memory[mt*32 + r5][kstep*16 + hi*8 + j] * rinv(row)), j = 0..7.
// ---------------------------------------------------------------------------
__global__ __launch_bounds__(256) void frag_kernel(const float* __restrict__ mem,
                                                   long* __restrict__ wsfrag) {
    int fid   = blockIdx.x * 256 + threadIdx.x;   // 0..8191
    int mt    = fid >> 9;
    int rem   = fid & 511;
    int kstep = rem >> 6;
    int l     = rem & 63;
    int hi    = l >> 5, r5 = l & 31;
    int row   = mt * 32 + r5;
    int k0    = kstep * 16 + hi * 8;

    const float* mr = mem + (size_t)row * CCH;
    float s = 0.f;
    #pragma unroll
    for (int c = 0; c < CCH; c += 4) {
        f4 v = *reinterpret_cast<const f4*>(mr + c);
        s += v.x * v.x + v.y * v.y + v.z * v.z + v.w * v.w;
    }
    float sc = 1.0f / fmaxf(sqrtf(s), 1e-12f);

    float v[8];
    #pragma unroll
    for (int j = 0; j < 8; ++j) v[j] = mr[k0 + j] * sc;
    wsfrag[fid] = pack_fp8x8(v);
}

// ---------------------------------------------------------------------------
// Main: 256 blocks x 16 waves, block owns 512 tokens. KEY CHANGE vs r16: the
// x-read is STORAGE-LINEAR f4 (1 KB contiguous per wave instruction — the
// shape the fill kernel proves sustains 6.7 TB/s) instead of 64 scalar loads
// at 16 KB stride per lane (128B bursts, DRAM-activation-bound ~1.2 TB/s in
// r12's isolated measurement). Values convert f32->fp8 in flight and land in
// a 64 KB LDS tile [c][t]; after one barrier each lane assembles fragments
// with broadcast-friendly byte reads and derives the token norm from the same
// fp8 data (threshold margin ~0.5*|x| dwarfs fp8 error). Fill keeps the
// proven-clean shape; hot loop + ballot + exact rare path unchanged.
// ---------------------------------------------------------------------------
__global__ __launch_bounds__(THREADS) void hardmem_mfma(
    const float* __restrict__ x, const float* __restrict__ mem,
    const long* __restrict__ wsfrag, float* __restrict__ out)
{
    __shared__ long sfrag[8192];            // 64 KB — fp8 row-fragment table
    __shared__ unsigned char xs8[65536];    // 64 KB — fp8 x tile [c][t], t=0..511

    const int tid  = threadIdx.x;
    const int wid  = tid >> 6;                 // 0..15
    const int lane = tid & 63;
    const int l5   = lane & 31, hi = lane >> 5;

    const int b    = blockIdx.x >> 3;                    // 8 blocks/batch
    const int treg = (blockIdx.x & 7) * 512;             // block token region
    const float* xb = x + (size_t)b * CCH * HWTOK + treg;
    float* obase    = out + (size_t)b * CCH * HWTOK;

    // ---- 1. zero-fill own region: 128 ch x 512 tok = 16384 f4.
    // Per wave instruction: 64 lanes x 16B = 1 KB contiguous (clean shape).
    {
        float* oreg = obase + treg;
        f4 z = {0.f, 0.f, 0.f, 0.f};
        #pragma unroll
        for (int i = 0; i < 16; ++i) {
            int idx = tid + i * THREADS;       // 0..16383
            int c = idx >> 7, o = idx & 127;
            *reinterpret_cast<f4*>(oreg + (size_t)c * HWTOK + o * 4) = z;
        }
    }

    // ---- 2. stage fp8 row table -> LDS (64 KB, L2-hot)
    {
        const i4* wsv = reinterpret_cast<const i4*>(wsfrag);
        i4* sfv = reinterpret_cast<i4*>(sfrag);
        #pragma unroll
        for (int i = 0; i < 4; ++i) {
            int idx = tid + i * THREADS;       // 0..4095 i4s
            sfv[idx] = wsv[idx];
        }
    }

    // ---- 3. stage x -> fp8 LDS tile, STORAGE-LINEAR reads.
    // idx = c*128 + o: lane-consecutive o -> 64 lanes x 16B = 1 KB contiguous
    // per instruction (half a 2 KB channel row). cvt f32->fp8 in flight;
    // ds_write_b32 at dword (c*128 + o): banks o%32, 2 lanes/bank = free.
    {
        unsigned* xsu = reinterpret_cast<unsigned*>(xs8);
        #pragma unroll
        for (int i = 0; i < 16; ++i) {
            int idx = tid + i * THREADS;       // 0..16383
            int c = idx >> 7, o = idx & 127;   // channel, f4-offset (4 tokens)
            f4 v = *reinterpret_cast<const f4*>(xb + (size_t)c * HWTOK + o * 4);
            int w = 0;
            w = __builtin_amdgcn_cvt_pk_fp8_f32(v.x, v.y, w, false);
            w = __builtin_amdgcn_cvt_pk_fp8_f32(v.z, v.w, w, true);
            xsu[c * 128 + o] = (unsigned)w;
        }
    }

    __syncthreads();   // LDS tiles ready + fill stores drained; below is
                       // wave-independent (no further block-wide syncs)

    // ---- 4. build x B-fragment + token norm from the fp8 tile.
    // byte addr = c*512 + t: 4 lanes share a dword (broadcast), halves 2-way.
    long bf[8];
    float n2;
    const int t = wid * 32 + l5;               // token within block region
    {
        float s = 0.f;
        #pragma unroll
        for (int k = 0; k < 8; ++k) {
            const int c0 = k * 16 + hi * 8;
            unsigned lo = 0, hi32 = 0;
            #pragma unroll
            for (int j = 0; j < 4; ++j)
                lo |= (unsigned)xs8[(c0 + j) * 512 + t] << (8 * j);
            #pragma unroll
            for (int j = 0; j < 4; ++j)
                hi32 |= (unsigned)xs8[(c0 + 4 + j) * 512 + t] << (8 * j);
            bf[k] = (long)lo | ((long)hi32 << 32);
            // norm contribution (order-insensitive): decode fp8 pairs
            f2 d0 = __builtin_amdgcn_cvt_pk_f32_fp8((int)lo, false);
            f2 d1 = __builtin_amdgcn_cvt_pk_f32_fp8((int)lo, true);
            f2 d2 = __builtin_amdgcn_cvt_pk_f32_fp8((int)hi32, false);
            f2 d3 = __builtin_amdgcn_cvt_pk_f32_fp8((int)hi32, true);
            s = fmaf(d0.x, d0.x, s); s = fmaf(d0.y, d0.y, s);
            s = fmaf(d1.x, d1.x, s); s = fmaf(d1.y, d1.y, s);
            s = fmaf(d2.x, d2.x, s); s = fmaf(d2.y, d2.y, s);
            s = fmaf(d3.x, d3.x, s); s = fmaf(d3.y, d3.y, s);
        }
        n2 = s + __shfl_xor(s, 32);            // halves hold half the channels
    }

    // ---- 5. hot loop: max-only over 512 rows, fp8 MFMA, A-frags from LDS
    float bmax = -1e30f;
    for (int mt = 0; mt < 16; ++mt) {
        long af[8];
        #pragma unroll
        for (int k = 0; k < 8; ++k)
            af[k] = sfrag[(mt * 8 + k) * 64 + lane];

        float16 acc;
        #pragma unroll
        for (int r = 0; r < 16; ++r) acc[r] = 0.f;
        #pragma unroll
        for (int k = 0; k < 8; ++k)
            acc = __builtin_amdgcn_mfma_f32_32x32x16_fp8_fp8(af[k], bf[k], acc, 0, 0, 0);

        float m0 = fmax3(acc[0], acc[1], acc[2]);
        float m1 = fmax3(acc[3], acc[4], acc[5]);
        float m2 = fmax3(acc[6], acc[7], acc[8]);
        float m3 = fmax3(acc[9], acc[10], acc[11]);
        float m4 = fmax3(acc[12], acc[13], acc[14]);
        bmax = fmaxf(bmax, fmax3(fmax3(m0, m1, m2), fmax3(m3, m4, acc[15]), bmax));
    }

    // ---- threshold: bv/||x|| > 0.8  <=>  bv > 0.8*||x|| (norm > 0)
    bmax = fmaxf(bmax, __shfl_xor(bmax, 32));   // merge hi-half rows
    const bool msk = bmax > 0.8f * fmaxf(sqrtf(n2), 1e-12f);

    const unsigned long long wb = __ballot(msk);
    if (wb == 0ULL) return;   // common case: zeros already in place

    // ---- rare path: exact argmax recompute (identical MFMAs), overwrite hits
    float bestv = -1e30f; int besti = 0;
    for (int mt = 0; mt < 16; ++mt) {
        long af[8];
        #pragma unroll
        for (int k = 0; k < 8; ++k)
            af[k] = sfrag[(mt * 8 + k) * 64 + lane];
        float16 acc;
        #pragma unroll
        for (int r = 0; r < 16; ++r) acc[r] = 0.f;
        #pragma unroll
        for (int k = 0; k < 8; ++k)
            acc = __builtin_amdgcn_mfma_f32_32x32x16_fp8_fp8(af[k], bf[k], acc, 0, 0, 0);
        const int rbase = mt * 32 + 4 * hi;
        #pragma unroll
        for (int r = 0; r < 16; ++r) {
            // C/D map (shape-determined): row=(reg&3)+8*(reg>>2)+4*(lane>>5)
            const int row = rbase + (r & 3) + 8 * (r >> 2);
            if (acc[r] > bestv) { bestv = acc[r]; besti = row; }
        }
    }
    float ov = __shfl_xor(bestv, 32);
    int   oi = __shfl_xor(besti, 32);
    if (ov > bestv || (ov == bestv && oi < besti)) { bestv = ov; besti = oi; }

    if (msk) {   // overwrite ONLY hit tokens (zeros elsewhere pre-filled)
        const int tt = treg + t;
        const float* mrow = mem + (size_t)besti * CCH;
        #pragma unroll 8
        for (int k = 0; k < 64; ++k) {
            int c = hi + 2 * k;
            obase[(size_t)c * HWTOK + tt] = mrow[c];
        }
    }
}

// ---------------------------------------------------------------------------
extern "C" void kernel_launch(void* const* d_in, const int* in_sizes, int n_in,
                              void* d_out, int out_size, void* d_ws, size_t ws_size,
                              hipStream_t stream) {
    const float* x   = (const float*)d_in[0];   // [32,128,64,64]
    const float* mem = (const float*)d_in[1];   // [512,128]
    float* out       = (float*)d_out;
    long* wsfrag     = (long*)d_ws;             // 64 KB fp8 fragment workspace

    frag_kernel<<<32, 256, 0, stream>>>(mem, wsfrag);
    hardmem_mfma<<<256, THREADS, 0, stream>>>(x, mem, wsfrag, out);
}